// Round 2
// baseline (1912.165 us; speedup 1.0000x reference)
//
#include <hip/hip_runtime.h>
#include <math.h>

#define D 1024
#define E 64
#define TOPK 6
#define NTOK 1024          // B*T = 2*512
#define F_R 704
#define F_S 1408
#define BK 16              // k-slice per LDS stage
#define XPAD 4             // pad transposed LDS tiles

// gemmA geometry: 256 thr, BM=128 rows x BN=64 cols, thread 8x4 per matrix (64 acc)
#define A_BM 128
#define A_BN 64
#define A_MT 2                         // mtiles -> cap 256 tokens/expert
#define A_FT_R (F_R / A_BN)            // 11
#define A_FT_S (F_S / A_BN)            // 22
#define A_RBLK (E * A_MT * A_FT_R)     // 1408 routed blocks
#define A_SBLK ((NTOK / A_BM) * A_FT_S) // 176 shared blocks

// gemmB geometry: 256 thr, BM=128 rows x BN=128 cols, thread 8x8 (64 acc)
#define B_BM 128
#define B_BN 128
#define B_MT 2
#define B_DT (D / B_BN)                // 8
#define B_RBLK (E * B_MT * B_DT)       // 1024
#define B_SBLK ((NTOK / B_BM) * B_DT)  // 64

__device__ __forceinline__ float sigm(float v) { return 1.f / (1.f + __expf(-v)); }

// ---------------- Gate ----------------
__global__ __launch_bounds__(64) void gate_kernel(
    const float* __restrict__ x, const float* __restrict__ wg,
    const float* __restrict__ gb, float* __restrict__ scores,
    int* __restrict__ sel_idx, float* __restrict__ sel_w)
{
    int t = blockIdx.x;
    int tid = threadIdx.x;
    __shared__ float xs[D];
    __shared__ float sc[E];
    for (int i = tid; i < D; i += 64) xs[i] = x[(size_t)t * D + i];
    __syncthreads();

    const float4* wrow = (const float4*)(wg + (size_t)tid * D);
    const float4* xv = (const float4*)xs;
    float acc = 0.f;
    for (int i = 0; i < D / 4; ++i) {
        float4 a = xv[i]; float4 b = wrow[i];
        acc += a.x * b.x + a.y * b.y + a.z * b.z + a.w * b.w;
    }
    float s = sigm(acc) + gb[tid];
    sc[tid] = s;
    scores[(size_t)t * E + tid] = s;
    __syncthreads();

    if (tid == 0) {
        int idxs[TOPK]; float vals[TOPK]; float wsum = 0.f;
        for (int k = 0; k < TOPK; ++k) {
            float best = -1e30f; int bi = 0;
            for (int e = 0; e < E; ++e) {
                if (sc[e] > best) { best = sc[e]; bi = e; }
            }
            sc[bi] = -1e30f;
            idxs[k] = bi; vals[k] = best; wsum += best;
        }
        float inv = 1.f / wsum;
        for (int k = 0; k < TOPK; ++k) {
            sel_idx[t * TOPK + k] = idxs[k];
            sel_w[t * TOPK + k] = vals[k] * inv;
        }
    }
}

// ---------------- Routing lists ----------------
__global__ void count_kernel(const int* __restrict__ sel_idx, int* __restrict__ counts) {
    int i = blockIdx.x * blockDim.x + threadIdx.x;
    if (i < NTOK * TOPK) atomicAdd(&counts[sel_idx[i]], 1);
}

__global__ void scan_kernel(const int* __restrict__ counts, int* __restrict__ offsets) {
    if (threadIdx.x == 0 && blockIdx.x == 0) {
        int run = 0;
        for (int e = 0; e < E; ++e) { offsets[e] = run; run += counts[e]; }
    }
}

__global__ void scatter_kernel(const int* __restrict__ sel_idx, const float* __restrict__ sel_w,
                               const int* __restrict__ offsets, int* __restrict__ cursor,
                               int* __restrict__ slot_tok, float* __restrict__ slot_w) {
    int i = blockIdx.x * blockDim.x + threadIdx.x;
    if (i < NTOK * TOPK) {
        int e = sel_idx[i];
        int pos = offsets[e] + atomicAdd(&cursor[e], 1);
        slot_tok[pos] = i / TOPK;
        slot_w[pos] = sel_w[i];
    }
}

// ---------------- GEMM A (merged routed+shared): G = silu(X@W1) * (X@W3) ----------------
// 1.0 B LDS-read per FMA: per k, 4 ds_read_b128 -> 64 FMAs.
__global__ __launch_bounds__(256, 3) void gemmA_all(
    const float* __restrict__ x,
    const float* __restrict__ w1r, const float* __restrict__ w3r,
    const float* __restrict__ w1s, const float* __restrict__ w3s,
    const int* __restrict__ offsets, const int* __restrict__ counts,
    const int* __restrict__ slot_tok,
    float* __restrict__ G_r, float* __restrict__ G_s)
{
    const int bid = blockIdx.x;
    int off, n, m0, f0, Fk;
    const float *w1p, *w3p;
    float* Gp;
    bool gather;
    if (bid < A_RBLK) {
        gather = true;
        int e   = bid / (A_MT * A_FT_R);
        int rem = bid % (A_MT * A_FT_R);
        int mt = rem / A_FT_R;
        int ft = rem % A_FT_R;
        off = offsets[e];
        n = counts[e]; if (n > A_BM * A_MT) n = A_BM * A_MT;
        m0 = mt * A_BM;
        f0 = ft * A_BN;
        Fk = F_R;
        w1p = w1r + (size_t)e * D * F_R;
        w3p = w3r + (size_t)e * D * F_R;
        Gp = G_r;
    } else {
        gather = false;
        int s  = bid - A_RBLK;
        int mt = s / A_FT_S;
        int ft = s % A_FT_S;
        off = 0; n = NTOK;
        m0 = mt * A_BM;
        f0 = ft * A_BN;
        Fk = F_S;
        w1p = w1s; w3p = w3s;
        Gp = G_s;
    }
    if (m0 >= n) return;
    const int rows = min(A_BM, n - m0);
    const int tid = threadIdx.x;
    const int tm4 = (tid & 15) * 4;   // rows tm4..+3 and tm4+64..+3
    const int tn4 = (tid >> 4) * 4;   // cols tn4..+3

    __shared__ float xs[2][BK][A_BM + XPAD];   // x transposed: xs[k][m]
    __shared__ float w1t[2][BK][A_BN];
    __shared__ float w3t[2][BK][A_BN];
    __shared__ int toks[A_BM];

    const int r0  = tid >> 2;         // 0..63 (second row = r0+64)
    const int c4  = (tid & 3) * 4;
    const int kw  = tid >> 4;         // 0..15
    const int cw4 = (tid & 15) * 4;

    if (tid < A_BM) {
        int rr = min(tid, rows - 1);
        toks[tid] = gather ? slot_tok[off + m0 + rr] : (m0 + rr);
    }
    __syncthreads();

    const float* xg0 = x + (size_t)toks[r0] * D + c4;
    const float* xg1 = x + (size_t)toks[r0 + 64] * D + c4;
    const size_t wstep = (size_t)BK * Fk;
    const float* w1g = w1p + (size_t)kw * Fk + f0 + cw4;
    const float* w3g = w3p + (size_t)kw * Fk + f0 + cw4;

    float4 xr0 = *(const float4*)xg0; xg0 += BK;
    float4 xr1 = *(const float4*)xg1; xg1 += BK;
    float4 ar  = *(const float4*)w1g; w1g += wstep;
    float4 br  = *(const float4*)w3g; w3g += wstep;

    float acc1[2][4][4], acc3[2][4][4];
#pragma unroll
    for (int h = 0; h < 2; ++h)
#pragma unroll
        for (int i = 0; i < 4; ++i)
#pragma unroll
            for (int j = 0; j < 4; ++j) { acc1[h][i][j] = 0.f; acc3[h][i][j] = 0.f; }

    int buf = 0;
    for (int k0 = 0; k0 < D; k0 += BK) {
        float (*xsb)[A_BM + XPAD] = xs[buf];
        float (*w1b)[A_BN] = w1t[buf];
        float (*w3b)[A_BN] = w3t[buf];
        xsb[c4 + 0][r0] = xr0.x; xsb[c4 + 1][r0] = xr0.y;
        xsb[c4 + 2][r0] = xr0.z; xsb[c4 + 3][r0] = xr0.w;
        xsb[c4 + 0][r0 + 64] = xr1.x; xsb[c4 + 1][r0 + 64] = xr1.y;
        xsb[c4 + 2][r0 + 64] = xr1.z; xsb[c4 + 3][r0 + 64] = xr1.w;
        *(float4*)&w1b[kw][cw4] = ar;
        *(float4*)&w3b[kw][cw4] = br;
        __syncthreads();
        if (k0 + BK < D) {
            xr0 = *(const float4*)xg0; xg0 += BK;
            xr1 = *(const float4*)xg1; xg1 += BK;
            ar  = *(const float4*)w1g; w1g += wstep;
            br  = *(const float4*)w3g; w3g += wstep;
        }
#pragma unroll
        for (int k = 0; k < BK; ++k) {
            float4 xv0 = *(const float4*)&xsb[k][tm4];
            float4 xv1 = *(const float4*)&xsb[k][tm4 + 64];
            float4 av  = *(const float4*)&w1b[k][tn4];
            float4 bv  = *(const float4*)&w3b[k][tn4];
            float xa0[4] = {xv0.x, xv0.y, xv0.z, xv0.w};
            float xa1[4] = {xv1.x, xv1.y, xv1.z, xv1.w};
            float aa[4]  = {av.x, av.y, av.z, av.w};
            float ba[4]  = {bv.x, bv.y, bv.z, bv.w};
#pragma unroll
            for (int i = 0; i < 4; ++i) {
#pragma unroll
                for (int j = 0; j < 4; ++j) {
                    acc1[0][i][j] = fmaf(xa0[i], aa[j], acc1[0][i][j]);
                    acc3[0][i][j] = fmaf(xa0[i], ba[j], acc3[0][i][j]);
                    acc1[1][i][j] = fmaf(xa1[i], aa[j], acc1[1][i][j]);
                    acc3[1][i][j] = fmaf(xa1[i], ba[j], acc3[1][i][j]);
                }
            }
        }
        buf ^= 1;
    }

#pragma unroll
    for (int h = 0; h < 2; ++h) {
#pragma unroll
        for (int i = 0; i < 4; ++i) {
            int rr = h * 64 + tm4 + i;
            if (rr < rows) {
                float4 g; float a;
                a = acc1[h][i][0]; g.x = a * (1.f / (1.f + __expf(-a))) * acc3[h][i][0];
                a = acc1[h][i][1]; g.y = a * (1.f / (1.f + __expf(-a))) * acc3[h][i][1];
                a = acc1[h][i][2]; g.z = a * (1.f / (1.f + __expf(-a))) * acc3[h][i][2];
                a = acc1[h][i][3]; g.w = a * (1.f / (1.f + __expf(-a))) * acc3[h][i][3];
                *(float4*)&Gp[(size_t)(off + m0 + rr) * Fk + f0 + tn4] = g;
            }
        }
    }
}

// ---------------- GEMM B (merged): out += w * (G @ W2), all-atomic epilogue ----------------
__global__ __launch_bounds__(256, 3) void gemmB_all(
    const float* __restrict__ G_r, const float* __restrict__ G_s,
    const float* __restrict__ w2r, const float* __restrict__ w2s,
    const int* __restrict__ offsets, const int* __restrict__ counts,
    const int* __restrict__ slot_tok, const float* __restrict__ slot_w,
    float* __restrict__ out)
{
    const int bid = blockIdx.x;
    int off, n, m0, d0, Fk;
    const float *Gp, *w2p;
    bool gather;
    if (bid < B_RBLK) {
        gather = true;
        int e   = bid / (B_MT * B_DT);
        int rem = bid % (B_MT * B_DT);
        int mt = rem / B_DT;
        int dt = rem % B_DT;
        off = offsets[e];
        n = counts[e]; if (n > B_BM * B_MT) n = B_BM * B_MT;
        m0 = mt * B_BM;
        d0 = dt * B_BN;
        Fk = F_R;
        Gp = G_r;
        w2p = w2r + (size_t)e * F_R * D;
    } else {
        gather = false;
        int s  = bid - B_RBLK;
        int mt = s / B_DT;
        int dt = s % B_DT;
        off = 0; n = NTOK;
        m0 = mt * B_BM;
        d0 = dt * B_BN;
        Fk = F_S;
        Gp = G_s;
        w2p = w2s;
    }
    if (m0 >= n) return;
    const int rows = min(B_BM, n - m0);
    const int tid = threadIdx.x;
    const int tm4 = (tid & 15) * 4;   // rows tm4, tm4+64
    const int tn4 = (tid >> 4) * 4;   // cols tn4, tn4+64

    __shared__ float gs[2][BK][B_BM + XPAD];   // G transposed: gs[k][m]
    __shared__ float wt[2][BK][B_BN + XPAD];

    const int r0 = tid >> 2;
    const int c4 = (tid & 3) * 4;
    const int kw = tid >> 4;
    const int cw = (tid & 15) * 8;

    const int rr0 = min(r0, rows - 1);
    const int rr1 = min(r0 + 64, rows - 1);
    const float* gg0 = Gp + (size_t)(off + m0 + rr0) * Fk + c4;
    const float* gg1 = Gp + (size_t)(off + m0 + rr1) * Fk + c4;
    const float* w2g = w2p + (size_t)kw * D + d0 + cw;

    float4 gr0 = *(const float4*)gg0; gg0 += BK;
    float4 gr1 = *(const float4*)gg1; gg1 += BK;
    float4 wr0 = *(const float4*)w2g;
    float4 wr1 = *(const float4*)(w2g + 4); w2g += (size_t)BK * D;

    float acc[2][2][4][4];
#pragma unroll
    for (int hm = 0; hm < 2; ++hm)
#pragma unroll
        for (int hn = 0; hn < 2; ++hn)
#pragma unroll
            for (int i = 0; i < 4; ++i)
#pragma unroll
                for (int j = 0; j < 4; ++j) acc[hm][hn][i][j] = 0.f;

    int buf = 0;
    for (int k0 = 0; k0 < Fk; k0 += BK) {
        float (*gsb)[B_BM + XPAD] = gs[buf];
        float (*wtb)[B_BN + XPAD] = wt[buf];
        gsb[c4 + 0][r0] = gr0.x; gsb[c4 + 1][r0] = gr0.y;
        gsb[c4 + 2][r0] = gr0.z; gsb[c4 + 3][r0] = gr0.w;
        gsb[c4 + 0][r0 + 64] = gr1.x; gsb[c4 + 1][r0 + 64] = gr1.y;
        gsb[c4 + 2][r0 + 64] = gr1.z; gsb[c4 + 3][r0 + 64] = gr1.w;
        *(float4*)&wtb[kw][cw]     = wr0;
        *(float4*)&wtb[kw][cw + 4] = wr1;
        __syncthreads();
        if (k0 + BK < Fk) {
            gr0 = *(const float4*)gg0; gg0 += BK;
            gr1 = *(const float4*)gg1; gg1 += BK;
            wr0 = *(const float4*)w2g;
            wr1 = *(const float4*)(w2g + 4); w2g += (size_t)BK * D;
        }
#pragma unroll
        for (int k = 0; k < BK; ++k) {
            float4 gv0 = *(const float4*)&gsb[k][tm4];
            float4 gv1 = *(const float4*)&gsb[k][tm4 + 64];
            float4 wv0 = *(const float4*)&wtb[k][tn4];
            float4 wv1 = *(const float4*)&wtb[k][tn4 + 64];
            float ga0[4] = {gv0.x, gv0.y, gv0.z, gv0.w};
            float ga1[4] = {gv1.x, gv1.y, gv1.z, gv1.w};
            float wa0[4] = {wv0.x, wv0.y, wv0.z, wv0.w};
            float wa1[4] = {wv1.x, wv1.y, wv1.z, wv1.w};
#pragma unroll
            for (int i = 0; i < 4; ++i) {
#pragma unroll
                for (int j = 0; j < 4; ++j) {
                    acc[0][0][i][j] = fmaf(ga0[i], wa0[j], acc[0][0][i][j]);
                    acc[0][1][i][j] = fmaf(ga0[i], wa1[j], acc[0][1][i][j]);
                    acc[1][0][i][j] = fmaf(ga1[i], wa0[j], acc[1][0][i][j]);
                    acc[1][1][i][j] = fmaf(ga1[i], wa1[j], acc[1][1][i][j]);
                }
            }
        }
        buf ^= 1;
    }

#pragma unroll
    for (int hm = 0; hm < 2; ++hm) {
#pragma unroll
        for (int i = 0; i < 4; ++i) {
            int rr = hm * 64 + tm4 + i;
            if (rr < rows) {
                int sl = off + m0 + rr;
                int tok = gather ? slot_tok[sl] : (m0 + rr);
                float tw = gather ? slot_w[sl] : 1.0f;
                float* op = out + (size_t)tok * D + d0;
#pragma unroll
                for (int hn = 0; hn < 2; ++hn) {
#pragma unroll
                    for (int j = 0; j < 4; ++j) {
                        atomicAdd(&op[hn * 64 + tn4 + j], tw * acc[hm][hn][i][j]);
                    }
                }
            }
        }
    }
}

// ---------------- Launch ----------------
extern "C" void kernel_launch(void* const* d_in, const int* in_sizes, int n_in,
                              void* d_out, int out_size, void* d_ws, size_t ws_size,
                              hipStream_t stream)
{
    const float* x   = (const float*)d_in[0];
    const float* wg  = (const float*)d_in[1];
    const float* gb  = (const float*)d_in[2];
    const float* w1s = (const float*)d_in[3];
    const float* w2s = (const float*)d_in[4];
    const float* w3s = (const float*)d_in[5];
    const float* w1r = (const float*)d_in[6];
    const float* w2r = (const float*)d_in[7];
    const float* w3r = (const float*)d_in[8];

    float* out = (float*)d_out;                 // [NTOK, D]
    float* scores = out + (size_t)NTOK * D;     // [NTOK, E]

    char* ws = (char*)d_ws;
    int*   sel_idx  = (int*)(ws + 0);           // 6144 ints
    float* sel_w    = (float*)(ws + 24576);     // 6144 floats
    int*   counts   = (int*)(ws + 49152);       // 64
    int*   cursor   = (int*)(ws + 49408);       // 64
    int*   offsets  = (int*)(ws + 49664);       // 64
    int*   slot_tok = (int*)(ws + 49920);       // 6144
    float* slot_w   = (float*)(ws + 74496);     // 6144
    float* G_r      = (float*)(ws + 131072);                                  // 6144*704 f32
    float* G_s      = (float*)(ws + 131072 + (size_t)NTOK * TOPK * F_R * 4);  // 1024*1408 f32

    hipMemsetAsync(counts, 0, 512, stream);             // counts + cursor
    hipMemsetAsync(out, 0, (size_t)NTOK * D * 4, stream); // out accumulated atomically

    gate_kernel<<<NTOK, 64, 0, stream>>>(x, wg, gb, scores, sel_idx, sel_w);
    count_kernel<<<24, 256, 0, stream>>>(sel_idx, counts);
    scan_kernel<<<1, 64, 0, stream>>>(counts, offsets);
    scatter_kernel<<<24, 256, 0, stream>>>(sel_idx, sel_w, offsets, cursor, slot_tok, slot_w);

    gemmA_all<<<A_RBLK + A_SBLK, 256, 0, stream>>>(
        x, w1r, w3r, w1s, w3s, offsets, counts, slot_tok, G_r, G_s);

    gemmB_all<<<B_RBLK + B_SBLK, 256, 0, stream>>>(
        G_r, G_s, w2r, w2s, offsets, counts, slot_tok, slot_w, out);
}

// Round 3
// 1903.729 us; speedup vs baseline: 1.0044x; 1.0044x over previous
//
#include <hip/hip_runtime.h>
#include <math.h>

#define D 1024
#define E 64
#define TOPK 6
#define NTOK 1024          // B*T = 2*512
#define F_R 704
#define F_S 1408
#define BK 16              // k-slice per LDS stage
#define XPAD 4             // pad transposed LDS tiles

// gemmA geometry: 256 thr, BM=128 rows x BN=64 cols, thread 8x4 per matrix (64 acc)
#define A_BM 128
#define A_BN 64
#define A_MT 2                         // mtiles -> cap 256 tokens/expert
#define A_FT_R (F_R / A_BN)            // 11
#define A_FT_S (F_S / A_BN)            // 22
#define A_RBLK (E * A_MT * A_FT_R)     // 1408 routed blocks
#define A_SBLK ((NTOK / A_BM) * A_FT_S) // 176 shared blocks

// gemmB geometry: 256 thr, BM=128 rows x BN=128 cols, thread 8x8 (64 acc)
#define B_BM 128
#define B_BN 128
#define B_MT 2
#define B_DT (D / B_BN)                // 8
#define B_RBLK (E * B_MT * B_DT)       // 1024
#define B_SBLK ((NTOK / B_BM) * B_DT)  // 64

__device__ __forceinline__ float sigm(float v) { return 1.f / (1.f + __expf(-v)); }

// ---------------- Gate ----------------
__global__ __launch_bounds__(64) void gate_kernel(
    const float* __restrict__ x, const float* __restrict__ wg,
    const float* __restrict__ gb, float* __restrict__ scores,
    int* __restrict__ sel_idx, float* __restrict__ sel_w)
{
    int t = blockIdx.x;
    int tid = threadIdx.x;
    __shared__ float xs[D];
    __shared__ float sc[E];
    for (int i = tid; i < D; i += 64) xs[i] = x[(size_t)t * D + i];
    __syncthreads();

    const float4* wrow = (const float4*)(wg + (size_t)tid * D);
    const float4* xv = (const float4*)xs;
    float acc = 0.f;
    for (int i = 0; i < D / 4; ++i) {
        float4 a = xv[i]; float4 b = wrow[i];
        acc += a.x * b.x + a.y * b.y + a.z * b.z + a.w * b.w;
    }
    float s = sigm(acc) + gb[tid];
    sc[tid] = s;
    scores[(size_t)t * E + tid] = s;
    __syncthreads();

    if (tid == 0) {
        int idxs[TOPK]; float vals[TOPK]; float wsum = 0.f;
        for (int k = 0; k < TOPK; ++k) {
            float best = -1e30f; int bi = 0;
            for (int e = 0; e < E; ++e) {
                if (sc[e] > best) { best = sc[e]; bi = e; }
            }
            sc[bi] = -1e30f;
            idxs[k] = bi; vals[k] = best; wsum += best;
        }
        float inv = 1.f / wsum;
        for (int k = 0; k < TOPK; ++k) {
            sel_idx[t * TOPK + k] = idxs[k];
            sel_w[t * TOPK + k] = vals[k] * inv;
        }
    }
}

// ---------------- Routing lists ----------------
__global__ void count_kernel(const int* __restrict__ sel_idx, int* __restrict__ counts) {
    int i = blockIdx.x * blockDim.x + threadIdx.x;
    if (i < NTOK * TOPK) atomicAdd(&counts[sel_idx[i]], 1);
}

__global__ void scan_kernel(const int* __restrict__ counts, int* __restrict__ offsets) {
    if (threadIdx.x == 0 && blockIdx.x == 0) {
        int run = 0;
        for (int e = 0; e < E; ++e) { offsets[e] = run; run += counts[e]; }
    }
}

__global__ void scatter_kernel(const int* __restrict__ sel_idx, const float* __restrict__ sel_w,
                               const int* __restrict__ offsets, int* __restrict__ cursor,
                               int* __restrict__ slot_tok, float* __restrict__ slot_w) {
    int i = blockIdx.x * blockDim.x + threadIdx.x;
    if (i < NTOK * TOPK) {
        int e = sel_idx[i];
        int pos = offsets[e] + atomicAdd(&cursor[e], 1);
        slot_tok[pos] = i / TOPK;
        slot_w[pos] = sel_w[i];
    }
}

// ---------------- GEMM A (merged routed+shared): G = silu(X@W1) * (X@W3) ----------------
// waves_per_eu(3,4): floor 3 (170-reg budget, pressure ~120 -> NO SPILLS possible),
// ceiling 4 stops clang's occupancy heuristic from squeezing to 85 regs + scratch
// (round-2 failure mode: VGPR=84, WRITE_SIZE=805MB of spill traffic).
__global__ __launch_bounds__(256) __attribute__((amdgpu_waves_per_eu(3, 4)))
void gemmA_all(
    const float* __restrict__ x,
    const float* __restrict__ w1r, const float* __restrict__ w3r,
    const float* __restrict__ w1s, const float* __restrict__ w3s,
    const int* __restrict__ offsets, const int* __restrict__ counts,
    const int* __restrict__ slot_tok,
    float* __restrict__ G_r, float* __restrict__ G_s)
{
    const int bid = blockIdx.x;
    int off, n, m0, f0, Fk;
    const float *w1p, *w3p;
    float* Gp;
    bool gather;
    if (bid < A_RBLK) {
        gather = true;
        int e   = bid / (A_MT * A_FT_R);
        int rem = bid % (A_MT * A_FT_R);
        int mt = rem / A_FT_R;
        int ft = rem % A_FT_R;
        off = offsets[e];
        n = counts[e]; if (n > A_BM * A_MT) n = A_BM * A_MT;
        m0 = mt * A_BM;
        f0 = ft * A_BN;
        Fk = F_R;
        w1p = w1r + (size_t)e * D * F_R;
        w3p = w3r + (size_t)e * D * F_R;
        Gp = G_r;
    } else {
        gather = false;
        int s  = bid - A_RBLK;
        int mt = s / A_FT_S;
        int ft = s % A_FT_S;
        off = 0; n = NTOK;
        m0 = mt * A_BM;
        f0 = ft * A_BN;
        Fk = F_S;
        w1p = w1s; w3p = w3s;
        Gp = G_s;
    }
    if (m0 >= n) return;
    const int rows = min(A_BM, n - m0);
    const int tid = threadIdx.x;
    const int tm4 = (tid & 15) * 4;   // rows tm4..+3 and tm4+64..+3
    const int tn4 = (tid >> 4) * 4;   // cols tn4..+3

    __shared__ float xs[2][BK][A_BM + XPAD];   // x transposed: xs[k][m]
    __shared__ float w1t[2][BK][A_BN];
    __shared__ float w3t[2][BK][A_BN];
    __shared__ int toks[A_BM];

    const int r0  = tid >> 2;         // 0..63 (second row = r0+64)
    const int c4  = (tid & 3) * 4;
    const int kw  = tid >> 4;         // 0..15
    const int cw4 = (tid & 15) * 4;

    if (tid < A_BM) {
        int rr = min(tid, rows - 1);
        toks[tid] = gather ? slot_tok[off + m0 + rr] : (m0 + rr);
    }
    __syncthreads();

    const float* xg0 = x + (size_t)toks[r0] * D + c4;
    const float* xg1 = x + (size_t)toks[r0 + 64] * D + c4;
    const size_t wstep = (size_t)BK * Fk;
    const float* w1g = w1p + (size_t)kw * Fk + f0 + cw4;
    const float* w3g = w3p + (size_t)kw * Fk + f0 + cw4;

    float4 xr0 = *(const float4*)xg0; xg0 += BK;
    float4 xr1 = *(const float4*)xg1; xg1 += BK;
    float4 ar  = *(const float4*)w1g; w1g += wstep;
    float4 br  = *(const float4*)w3g; w3g += wstep;

    float acc1[2][4][4], acc3[2][4][4];
#pragma unroll
    for (int h = 0; h < 2; ++h)
#pragma unroll
        for (int i = 0; i < 4; ++i)
#pragma unroll
            for (int j = 0; j < 4; ++j) { acc1[h][i][j] = 0.f; acc3[h][i][j] = 0.f; }

    int buf = 0;
    for (int k0 = 0; k0 < D; k0 += BK) {
        float (*xsb)[A_BM + XPAD] = xs[buf];
        float (*w1b)[A_BN] = w1t[buf];
        float (*w3b)[A_BN] = w3t[buf];
        xsb[c4 + 0][r0] = xr0.x; xsb[c4 + 1][r0] = xr0.y;
        xsb[c4 + 2][r0] = xr0.z; xsb[c4 + 3][r0] = xr0.w;
        xsb[c4 + 0][r0 + 64] = xr1.x; xsb[c4 + 1][r0 + 64] = xr1.y;
        xsb[c4 + 2][r0 + 64] = xr1.z; xsb[c4 + 3][r0 + 64] = xr1.w;
        *(float4*)&w1b[kw][cw4] = ar;
        *(float4*)&w3b[kw][cw4] = br;
        __syncthreads();
        if (k0 + BK < D) {
            xr0 = *(const float4*)xg0; xg0 += BK;
            xr1 = *(const float4*)xg1; xg1 += BK;
            ar  = *(const float4*)w1g; w1g += wstep;
            br  = *(const float4*)w3g; w3g += wstep;
        }
#pragma unroll
        for (int k = 0; k < BK; ++k) {
            float4 xv0 = *(const float4*)&xsb[k][tm4];
            float4 xv1 = *(const float4*)&xsb[k][tm4 + 64];
            float4 av  = *(const float4*)&w1b[k][tn4];
            float4 bv  = *(const float4*)&w3b[k][tn4];
            float xa0[4] = {xv0.x, xv0.y, xv0.z, xv0.w};
            float xa1[4] = {xv1.x, xv1.y, xv1.z, xv1.w};
            float aa[4]  = {av.x, av.y, av.z, av.w};
            float ba[4]  = {bv.x, bv.y, bv.z, bv.w};
#pragma unroll
            for (int i = 0; i < 4; ++i) {
#pragma unroll
                for (int j = 0; j < 4; ++j) {
                    acc1[0][i][j] = fmaf(xa0[i], aa[j], acc1[0][i][j]);
                    acc3[0][i][j] = fmaf(xa0[i], ba[j], acc3[0][i][j]);
                    acc1[1][i][j] = fmaf(xa1[i], aa[j], acc1[1][i][j]);
                    acc3[1][i][j] = fmaf(xa1[i], ba[j], acc3[1][i][j]);
                }
            }
        }
        buf ^= 1;
    }

#pragma unroll
    for (int h = 0; h < 2; ++h) {
#pragma unroll
        for (int i = 0; i < 4; ++i) {
            int rr = h * 64 + tm4 + i;
            if (rr < rows) {
                float4 g; float a;
                a = acc1[h][i][0]; g.x = a * (1.f / (1.f + __expf(-a))) * acc3[h][i][0];
                a = acc1[h][i][1]; g.y = a * (1.f / (1.f + __expf(-a))) * acc3[h][i][1];
                a = acc1[h][i][2]; g.z = a * (1.f / (1.f + __expf(-a))) * acc3[h][i][2];
                a = acc1[h][i][3]; g.w = a * (1.f / (1.f + __expf(-a))) * acc3[h][i][3];
                *(float4*)&Gp[(size_t)(off + m0 + rr) * Fk + f0 + tn4] = g;
            }
        }
    }
}

// ---------------- GEMM B (merged): out += w * (G @ W2), all-atomic epilogue ----------------
__global__ __launch_bounds__(256) __attribute__((amdgpu_waves_per_eu(3, 4)))
void gemmB_all(
    const float* __restrict__ G_r, const float* __restrict__ G_s,
    const float* __restrict__ w2r, const float* __restrict__ w2s,
    const int* __restrict__ offsets, const int* __restrict__ counts,
    const int* __restrict__ slot_tok, const float* __restrict__ slot_w,
    float* __restrict__ out)
{
    const int bid = blockIdx.x;
    int off, n, m0, d0, Fk;
    const float *Gp, *w2p;
    bool gather;
    if (bid < B_RBLK) {
        gather = true;
        int e   = bid / (B_MT * B_DT);
        int rem = bid % (B_MT * B_DT);
        int mt = rem / B_DT;
        int dt = rem % B_DT;
        off = offsets[e];
        n = counts[e]; if (n > B_BM * B_MT) n = B_BM * B_MT;
        m0 = mt * B_BM;
        d0 = dt * B_BN;
        Fk = F_R;
        Gp = G_r;
        w2p = w2r + (size_t)e * F_R * D;
    } else {
        gather = false;
        int s  = bid - B_RBLK;
        int mt = s / B_DT;
        int dt = s % B_DT;
        off = 0; n = NTOK;
        m0 = mt * B_BM;
        d0 = dt * B_BN;
        Fk = F_S;
        Gp = G_s;
        w2p = w2s;
    }
    if (m0 >= n) return;
    const int rows = min(B_BM, n - m0);
    const int tid = threadIdx.x;
    const int tm4 = (tid & 15) * 4;   // rows tm4, tm4+64
    const int tn4 = (tid >> 4) * 4;   // cols tn4, tn4+64

    __shared__ float gs[2][BK][B_BM + XPAD];   // G transposed: gs[k][m]
    __shared__ float wt[2][BK][B_BN + XPAD];

    const int r0 = tid >> 2;
    const int c4 = (tid & 3) * 4;
    const int kw = tid >> 4;
    const int cw = (tid & 15) * 8;

    const int rr0 = min(r0, rows - 1);
    const int rr1 = min(r0 + 64, rows - 1);
    const float* gg0 = Gp + (size_t)(off + m0 + rr0) * Fk + c4;
    const float* gg1 = Gp + (size_t)(off + m0 + rr1) * Fk + c4;
    const float* w2g = w2p + (size_t)kw * D + d0 + cw;

    float4 gr0 = *(const float4*)gg0; gg0 += BK;
    float4 gr1 = *(const float4*)gg1; gg1 += BK;
    float4 wr0 = *(const float4*)w2g;
    float4 wr1 = *(const float4*)(w2g + 4); w2g += (size_t)BK * D;

    float acc[2][2][4][4];
#pragma unroll
    for (int hm = 0; hm < 2; ++hm)
#pragma unroll
        for (int hn = 0; hn < 2; ++hn)
#pragma unroll
            for (int i = 0; i < 4; ++i)
#pragma unroll
                for (int j = 0; j < 4; ++j) acc[hm][hn][i][j] = 0.f;

    int buf = 0;
    for (int k0 = 0; k0 < Fk; k0 += BK) {
        float (*gsb)[B_BM + XPAD] = gs[buf];
        float (*wtb)[B_BN + XPAD] = wt[buf];
        gsb[c4 + 0][r0] = gr0.x; gsb[c4 + 1][r0] = gr0.y;
        gsb[c4 + 2][r0] = gr0.z; gsb[c4 + 3][r0] = gr0.w;
        gsb[c4 + 0][r0 + 64] = gr1.x; gsb[c4 + 1][r0 + 64] = gr1.y;
        gsb[c4 + 2][r0 + 64] = gr1.z; gsb[c4 + 3][r0 + 64] = gr1.w;
        *(float4*)&wtb[kw][cw]     = wr0;
        *(float4*)&wtb[kw][cw + 4] = wr1;
        __syncthreads();
        if (k0 + BK < Fk) {
            gr0 = *(const float4*)gg0; gg0 += BK;
            gr1 = *(const float4*)gg1; gg1 += BK;
            wr0 = *(const float4*)w2g;
            wr1 = *(const float4*)(w2g + 4); w2g += (size_t)BK * D;
        }
#pragma unroll
        for (int k = 0; k < BK; ++k) {
            float4 gv0 = *(const float4*)&gsb[k][tm4];
            float4 gv1 = *(const float4*)&gsb[k][tm4 + 64];
            float4 wv0 = *(const float4*)&wtb[k][tn4];
            float4 wv1 = *(const float4*)&wtb[k][tn4 + 64];
            float ga0[4] = {gv0.x, gv0.y, gv0.z, gv0.w};
            float ga1[4] = {gv1.x, gv1.y, gv1.z, gv1.w};
            float wa0[4] = {wv0.x, wv0.y, wv0.z, wv0.w};
            float wa1[4] = {wv1.x, wv1.y, wv1.z, wv1.w};
#pragma unroll
            for (int i = 0; i < 4; ++i) {
#pragma unroll
                for (int j = 0; j < 4; ++j) {
                    acc[0][0][i][j] = fmaf(ga0[i], wa0[j], acc[0][0][i][j]);
                    acc[0][1][i][j] = fmaf(ga0[i], wa1[j], acc[0][1][i][j]);
                    acc[1][0][i][j] = fmaf(ga1[i], wa0[j], acc[1][0][i][j]);
                    acc[1][1][i][j] = fmaf(ga1[i], wa1[j], acc[1][1][i][j]);
                }
            }
        }
        buf ^= 1;
    }

#pragma unroll
    for (int hm = 0; hm < 2; ++hm) {
#pragma unroll
        for (int i = 0; i < 4; ++i) {
            int rr = hm * 64 + tm4 + i;
            if (rr < rows) {
                int sl = off + m0 + rr;
                int tok = gather ? slot_tok[sl] : (m0 + rr);
                float tw = gather ? slot_w[sl] : 1.0f;
                float* op = out + (size_t)tok * D + d0;
#pragma unroll
                for (int hn = 0; hn < 2; ++hn) {
#pragma unroll
                    for (int j = 0; j < 4; ++j) {
                        atomicAdd(&op[hn * 64 + tn4 + j], tw * acc[hm][hn][i][j]);
                    }
                }
            }
        }
    }
}

// ---------------- Launch ----------------
extern "C" void kernel_launch(void* const* d_in, const int* in_sizes, int n_in,
                              void* d_out, int out_size, void* d_ws, size_t ws_size,
                              hipStream_t stream)
{
    const float* x   = (const float*)d_in[0];
    const float* wg  = (const float*)d_in[1];
    const float* gb  = (const float*)d_in[2];
    const float* w1s = (const float*)d_in[3];
    const float* w2s = (const float*)d_in[4];
    const float* w3s = (const float*)d_in[5];
    const float* w1r = (const float*)d_in[6];
    const float* w2r = (const float*)d_in[7];
    const float* w3r = (const float*)d_in[8];

    float* out = (float*)d_out;                 // [NTOK, D]
    float* scores = out + (size_t)NTOK * D;     // [NTOK, E]

    char* ws = (char*)d_ws;
    int*   sel_idx  = (int*)(ws + 0);           // 6144 ints
    float* sel_w    = (float*)(ws + 24576);     // 6144 floats
    int*   counts   = (int*)(ws + 49152);       // 64
    int*   cursor   = (int*)(ws + 49408);       // 64
    int*   offsets  = (int*)(ws + 49664);       // 64
    int*   slot_tok = (int*)(ws + 49920);       // 6144
    float* slot_w   = (float*)(ws + 74496);     // 6144
    float* G_r      = (float*)(ws + 131072);                                  // 6144*704 f32
    float* G_s      = (float*)(ws + 131072 + (size_t)NTOK * TOPK * F_R * 4);  // 1024*1408 f32

    hipMemsetAsync(counts, 0, 512, stream);             // counts + cursor
    hipMemsetAsync(out, 0, (size_t)NTOK * D * 4, stream); // out accumulated atomically

    gate_kernel<<<NTOK, 64, 0, stream>>>(x, wg, gb, scores, sel_idx, sel_w);
    count_kernel<<<24, 256, 0, stream>>>(sel_idx, counts);
    scan_kernel<<<1, 64, 0, stream>>>(counts, offsets);
    scatter_kernel<<<24, 256, 0, stream>>>(sel_idx, sel_w, offsets, cursor, slot_tok, slot_w);

    gemmA_all<<<A_RBLK + A_SBLK, 256, 0, stream>>>(
        x, w1r, w3r, w1s, w3s, offsets, counts, slot_tok, G_r, G_s);

    gemmB_all<<<B_RBLK + B_SBLK, 256, 0, stream>>>(
        G_r, G_s, w2r, w2s, offsets, counts, slot_tok, slot_w, out);
}